// Round 3
// baseline (161.871 us; speedup 1.0000x reference)
//
#include <hip/hip_runtime.h>
#include <stdint.h>

typedef _Float16 half8 __attribute__((ext_vector_type(8)));
typedef float f32x16 __attribute__((ext_vector_type(16)));

// ---------------- sizes ----------------
// F  : per-pixel-channel features, fp16. p = ((b*66+h)*66+w)*32 + c ; F[p*18 + m]
//      m=0..16 hat_m(clip(x)) on grid -1..1 (h=0.125), m=17 silu(x)
//      => per pixel (b,h,w): 576 contiguous halves, k = c*18 + m
// th : theta^T fp16, [i(3)][f(64)][k(1728)], k = j*576 + c*18 + m
//      m<17: w_spline*cp[m] ; m==17: w_silu
#define NPX  (4 * 66 * 66 * 32)          // 557568
#define NTH  (3 * 64 * 1728)             // 331776
#define TH_OFF_BYTES ((size_t)NPX * 18 * 2)   // 20,072,448
#define PREP_BLOCKS  ((NPX + NTH) / 256)      // 3474 exactly

__global__ __launch_bounds__(256) void kan_prep(
    const float* __restrict__ x, const float* __restrict__ cp,
    const float* __restrict__ wspl, const float* __restrict__ wsil,
    _Float16* __restrict__ Ff, _Float16* __restrict__ th)
{
    int tid = blockIdx.x * 256 + threadIdx.x;
    if (tid < NPX) {
        float p  = x[tid];
        float xc = fminf(1.0f, fmaxf(-1.0f, p));
        float u  = fmaf(xc, 8.0f, 8.0f);                    // [0,16]
        union { _Float16 h[18]; uint32_t w[9]; } pk;
#pragma unroll
        for (int m = 0; m < 17; ++m)
            pk.h[m] = (_Float16)fmaxf(0.0f, 1.0f - fabsf(u - (float)m));
        pk.h[17] = (_Float16)(p * __builtin_amdgcn_rcpf(1.0f + __expf(-p)));
        uint32_t* dst = (uint32_t*)(Ff + (size_t)tid * 18);
#pragma unroll
        for (int q = 0; q < 9; ++q) dst[q] = pk.w[q];
    } else if (tid < NPX + NTH) {
        int e  = tid - NPX;
        int k  = e % 1728;
        int fi = e / 1728;
        int f  = fi & 63;
        int i  = fi >> 6;
        int j  = k / 576;
        int q  = k - j * 576;
        int c  = q / 18;
        int m  = q - c * 18;
        int base = ((f * 32 + c) * 3 + i) * 3 + j;           // (F,C,3,3) flat
        float v = (m < 17) ? wspl[base] * cp[base * 17 + m] : wsil[base];
        th[e] = (_Float16)v;
    }
}

// GEMM main, LDS-FREE: MFMA fragments are loaded DIRECTLY from global.
// Fragment pattern (verified via the prior LDS kernel's staging algebra):
//   A lane l: row = px (l&31), 16B at k = t*64 + s*16 + (l>>5)*8
//   B lane l: row = f  (l&31), same k offsets
// Both Ff (576/row) and th (1728/row) have K contiguous per row, and the
// im2col j-shift is exactly +576 halves for BOTH => whole K=1728 loop is
// two pointers advancing +64 halves (128 B) per chunk t = 0..26.
// Block = 128 thr = 2 waves: wave wv owns f-half wv (32f), both waves share
// the same 32 px (A loads duplicated, L1-served). Grid = 512 px-groups x 3 i
// => 1536 blocks = 6 blocks/CU = 12 waves/CU, no barriers, free-running.
__global__ __launch_bounds__(128) void kan_main(
    const _Float16* __restrict__ Ff, const _Float16* __restrict__ th,
    const float* __restrict__ bias, float* __restrict__ out)
{
    const int bid = blockIdx.x;
    const int i  = bid % 3;                  // kernel row 0..2
    const int g  = bid / 3;                  // px group 0..511
    const int h2 = g & 1;                    // w half (0: w 0..31, 1: 32..63)
    const int ho = (g >> 1) & 63;            // output row
    const int b  = g >> 7;                   // batch

    const int tid  = threadIdx.x;
    const int wv   = tid >> 6;               // f-half
    const int lane = tid & 63;
    const int r31  = lane & 31;
    const int kh   = lane >> 5;

    // A: pixel (b, ho+i, h2*32 + r31 + j); j folded into the k-walk (+576).
    const _Float16* pA = Ff
        + ((size_t)((b * 66 + ho + i) * 66 + h2 * 32 + r31)) * 576 + kh * 8;
    // B: th row f = i*64-group, f = wv*32 + r31
    const _Float16* pB = th
        + ((size_t)(i * 64 + wv * 32 + r31)) * 1728 + kh * 8;

    f32x16 acc;
    {
        float bv = (i == 1) ? bias[wv * 32 + r31] : 0.0f;
#pragma unroll
        for (int r = 0; r < 16; ++r) acc[r] = bv;
    }

#define LD(t, A0, A1, A2, A3, B0, B1, B2, B3)                                  \
    {                                                                          \
        const _Float16* qa = pA + (t) * 64;                                    \
        const _Float16* qb = pB + (t) * 64;                                    \
        A0 = *(const half8*)(qa);      A1 = *(const half8*)(qa + 16);          \
        A2 = *(const half8*)(qa + 32); A3 = *(const half8*)(qa + 48);          \
        B0 = *(const half8*)(qb);      B1 = *(const half8*)(qb + 16);          \
        B2 = *(const half8*)(qb + 32); B3 = *(const half8*)(qb + 48);          \
    }

    half8 a0, a1, a2, a3, b0, b1, b2, b3;
    half8 na0, na1, na2, na3, nb0, nb1, nb2, nb3;
    LD(0, a0, a1, a2, a3, b0, b1, b2, b3)

#pragma unroll
    for (int t = 0; t < 27; ++t) {
        if (t < 26) LD(t + 1, na0, na1, na2, na3, nb0, nb1, nb2, nb3)
        acc = __builtin_amdgcn_mfma_f32_32x32x16_f16(a0, b0, acc, 0, 0, 0);
        acc = __builtin_amdgcn_mfma_f32_32x32x16_f16(a1, b1, acc, 0, 0, 0);
        acc = __builtin_amdgcn_mfma_f32_32x32x16_f16(a2, b2, acc, 0, 0, 0);
        acc = __builtin_amdgcn_mfma_f32_32x32x16_f16(a3, b3, acc, 0, 0, 0);
        a0 = na0; a1 = na1; a2 = na2; a3 = na3;
        b0 = nb0; b1 = nb1; b2 = nb2; b3 = nb3;
    }
#undef LD

    // C/D layout (verified): col = lane&31 (f-local), row = (reg&3)+8*(reg>>2)+4*(lane>>5)
    float* obase = out + ((size_t)((b * 64 + ho) * 64 + h2 * 32)) * 64 + wv * 32;
#pragma unroll
    for (int r = 0; r < 16; ++r) {
        int rowD = (r & 3) + 8 * (r >> 2) + 4 * kh;   // px within the 32-block
        atomicAdd(obase + (size_t)rowD * 64 + r31, acc[r]);
    }
}

extern "C" void kernel_launch(void* const* d_in, const int* in_sizes, int n_in,
                              void* d_out, int out_size, void* d_ws, size_t ws_size,
                              hipStream_t stream) {
    const float* x    = (const float*)d_in[0];
    const float* cp   = (const float*)d_in[1];
    const float* wspl = (const float*)d_in[2];
    const float* wsil = (const float*)d_in[3];
    const float* bias = (const float*)d_in[4];
    float* out = (float*)d_out;

    uint8_t* ws = (uint8_t*)d_ws;
    _Float16* Ff = (_Float16*)ws;
    _Float16* th = (_Float16*)(ws + TH_OFF_BYTES);

    kan_prep<<<PREP_BLOCKS, 256, 0, stream>>>(x, cp, wspl, wsil, Ff, th);
    hipMemsetAsync(d_out, 0, (size_t)out_size * 4, stream);

    kan_main<<<1536, 128, 0, stream>>>(Ff, th, bias, out);
}

// Round 4
// 106.280 us; speedup vs baseline: 1.5231x; 1.5231x over previous
//
#include <hip/hip_runtime.h>
#include <stdint.h>

typedef _Float16 half8 __attribute__((ext_vector_type(8)));
typedef float f32x16 __attribute__((ext_vector_type(16)));

// ---------------- sizes ----------------
// F  : per-pixel-channel features, fp16. p = ((b*66+h)*66+w)*32 + c ; F[p*18 + m]
//      m=0..16 hat_m(clip(x)) on grid -1..1 (h=0.125), m=17 silu(x)
//      => per pixel (b,h,w): 576 contiguous halves, k = c*18 + m
//      => A row for output px (b,h,w) is the CONTIGUOUS 1728-half slice
//         Ff[((b,h,w))*576 + k], k = j*576 + c*18 + m  (windows overlap in w)
// th : theta^T fp16, [i(3)][f(64)][k(1728)], k = j*576 + c*18 + m
//      m<17: w_spline*cp[m] ; m==17: w_silu
#define NPX  (4 * 66 * 66 * 32)          // 557568
#define NTH  (3 * 64 * 1728)             // 331776
#define TH_OFF_BYTES ((size_t)NPX * 18 * 2)   // 20,072,448
#define PREP_BLOCKS  ((NPX + NTH) / 256)      // 3474 exactly

__global__ __launch_bounds__(256) void kan_prep(
    const float* __restrict__ x, const float* __restrict__ cp,
    const float* __restrict__ wspl, const float* __restrict__ wsil,
    _Float16* __restrict__ Ff, _Float16* __restrict__ th)
{
    int tid = blockIdx.x * 256 + threadIdx.x;
    if (tid < NPX) {
        float p  = x[tid];
        float xc = fminf(1.0f, fmaxf(-1.0f, p));
        float u  = fmaf(xc, 8.0f, 8.0f);                    // [0,16]
        union { _Float16 h[18]; uint32_t w[9]; } pk;
#pragma unroll
        for (int m = 0; m < 17; ++m)
            pk.h[m] = (_Float16)fmaxf(0.0f, 1.0f - fabsf(u - (float)m));
        pk.h[17] = (_Float16)(p * __builtin_amdgcn_rcpf(1.0f + __expf(-p)));
        uint32_t* dst = (uint32_t*)(Ff + (size_t)tid * 18);
#pragma unroll
        for (int q = 0; q < 9; ++q) dst[q] = pk.w[q];
    } else if (tid < NPX + NTH) {
        int e  = tid - NPX;
        int k  = e % 1728;
        int fi = e / 1728;
        int f  = fi & 63;
        int i  = fi >> 6;
        int j  = k / 576;
        int q  = k - j * 576;
        int c  = q / 18;
        int m  = q - c * 18;
        int base = ((f * 32 + c) * 3 + i) * 3 + j;           // (F,C,3,3) flat
        float v = (m < 17) ? wspl[base] * cp[base * 17 + m] : wsil[base];
        th[e] = (_Float16)v;
    }
}

// GEMM main: block = 256 thr = 4 waves = 2 px-halves x 2 f-halves.
// Tile 64 px (one output row) x 64 f, one i-group; grid (256, 3) => 768
// blocks x 4 waves = 12 waves/CU (2x the 128-thr version that measured
// Occupancy 12.7%, MfmaUtil 8.5% -- latency-bound on staging).
// K = 1728 per i, chunks of 64; A/B rows are contiguous K slices so the
// chunk walk is pointer + 128 B. LDS rows padded to 72 halves (144 B):
// measured 0 bank conflicts with this pad. Double-buffered, ONE barrier
// per chunk; next chunk's global loads issued after the barrier so they
// fly under ds_read+MFMA.
__global__ __launch_bounds__(256) void kan_main(
    const _Float16* __restrict__ Ff, const _Float16* __restrict__ th,
    const float* __restrict__ bias, float* __restrict__ out)
{
    __shared__ _Float16 lA[2][64 * 72];            // 2 x 9216 B
    __shared__ _Float16 lB[2][64 * 72];            // 2 x 9216 B

    const int bx = blockIdx.x;                     // b = bx>>6, ho = bx&63
    const int i  = blockIdx.y;                     // 0..2
    const int b  = bx >> 6;
    const int ho = bx & 63;

    const int tid  = threadIdx.x;                  // 0..255
    const int wv   = tid >> 6;                     // wave 0..3
    const int wpx  = wv >> 1;                      // px half (0: px 0..31)
    const int wf   = wv & 1;                       // f half  (0: f 0..31)
    const int lane = tid & 63;
    const int r31  = lane & 31;
    const int kh   = lane >> 5;

    const int srow = tid >> 2;                     // staging row 0..63
    const int sq   = tid & 3;                      // 32B quarter of the row

    // A row srow = output px (b, ho+i, w=srow); contiguous 1728-half slice.
    const _Float16* gA = Ff
        + ((size_t)((b * 66 + ho + i) * 66 + srow)) * 576 + sq * 16;
    const _Float16* gB = th
        + ((size_t)(i * 64 + srow)) * 1728 + sq * 16;

    uint4 pA0, pA1, pB0, pB1;
#define LOADCH(ch)                                                \
    {                                                             \
        const uint4* qa = (const uint4*)(gA + (ch) * 64);         \
        pA0 = qa[0]; pA1 = qa[1];                                 \
        const uint4* qb = (const uint4*)(gB + (ch) * 64);         \
        pB0 = qb[0]; pB1 = qb[1];                                 \
    }

    LOADCH(0)

    f32x16 acc;
    {
        float bv = (i == 1) ? bias[wf * 32 + r31] : 0.0f;
#pragma unroll
        for (int r = 0; r < 16; ++r) acc[r] = bv;
    }

    const int aoff = (wpx * 32 + r31) * 72 + kh * 8;   // fragment offsets
    const int boff = (wf  * 32 + r31) * 72 + kh * 8;
    char* wbA = (char*)lA[0] + srow * 144 + sq * 32;   // staging write base
    char* wbB = (char*)lB[0] + srow * 144 + sq * 32;

    int cur = 0;
    for (int ch = 0; ch < 27; ++ch) {
        uint4* dA = (uint4*)(wbA + cur * 9216);
        uint4* dB = (uint4*)(wbB + cur * 9216);
        dA[0] = pA0; dA[1] = pA1;
        dB[0] = pB0; dB[1] = pB1;
        __syncthreads();                           // buf[cur] visible
        if (ch < 26) LOADCH(ch + 1)                // in flight under compute
        const _Float16* pa = lA[cur] + aoff;
        const _Float16* pb = lB[cur] + boff;
#pragma unroll
        for (int s = 0; s < 4; ++s) {
            half8 a  = *(const half8*)(pa + s * 16);
            half8 bf = *(const half8*)(pb + s * 16);
            acc = __builtin_amdgcn_mfma_f32_32x32x16_f16(a, bf, acc, 0, 0, 0);
        }
        cur ^= 1;
    }
#undef LOADCH

    // C/D layout (verified): col = lane&31, row = (reg&3)+8*(reg>>2)+4*(lane>>5)
    float* obase = out
        + ((size_t)((b * 64 + ho) * 64 + wpx * 32)) * 64 + wf * 32;
#pragma unroll
    for (int r = 0; r < 16; ++r) {
        int rowD = (r & 3) + 8 * (r >> 2) + 4 * kh;  // px within the 32-block
        atomicAdd(obase + (size_t)rowD * 64 + r31, acc[r]);
    }
}

extern "C" void kernel_launch(void* const* d_in, const int* in_sizes, int n_in,
                              void* d_out, int out_size, void* d_ws, size_t ws_size,
                              hipStream_t stream) {
    const float* x    = (const float*)d_in[0];
    const float* cp   = (const float*)d_in[1];
    const float* wspl = (const float*)d_in[2];
    const float* wsil = (const float*)d_in[3];
    const float* bias = (const float*)d_in[4];
    float* out = (float*)d_out;

    uint8_t* ws = (uint8_t*)d_ws;
    _Float16* Ff = (_Float16*)ws;
    _Float16* th = (_Float16*)(ws + TH_OFF_BYTES);

    kan_prep<<<PREP_BLOCKS, 256, 0, stream>>>(x, cp, wspl, wsil, Ff, th);
    hipMemsetAsync(d_out, 0, (size_t)out_size * 4, stream);

    dim3 grid(256, 3);
    kan_main<<<grid, 256, 0, stream>>>(Ff, th, bias, out);
}